// Round 4
// baseline (8857.991 us; speedup 1.0000x reference)
//
#include <hip/hip_runtime.h>
#include <math.h>
#include <float.h>

#define N_ROWS 131072
#define DIM 64
#define KM1 1023
#define KPAD 1024

// ---- ws layout (bytes) ----
#define DT_OFF   0         // float[64][1024] transposed, pre-doubled dith
#define D2_OFF   262144    // float[1024]
#define ZS_OFF   266240    // float[131072] zsum
#define CNT_OFF  790528    // u32[1024]
#define IDX_OFF  794624    // i32[131072]
// total 1318912 B

// Opacity guard: stops ffp-contract=fast from changing rounding vs numpy.
#define OPQ(x) asm volatile("" : "+v"(x))

__device__ __forceinline__ float lerp_exact(float lo, float hi, float tt) {
    float hl = __fsub_rn(hi, lo);
    float p  = __fmul_rn(tt, hl);
    OPQ(p);
    float dv = __fadd_rn(lo, p);
    OPQ(dv);
    return dv;
}

// Kernel A: dither + transpose (pre-doubled) + d2 (numpy pairwise) + zero counts.
// 16 blocks x 256; block b covers k in [64b, 64b+64).
__global__ void __launch_bounds__(256)
prep_kernel(const float* __restrict__ cb, const float* __restrict__ dither,
            float* __restrict__ dithT, float* __restrict__ d2,
            unsigned* __restrict__ counts) {
    __shared__ float S[64 * 65];
    const int t = threadIdx.x, b = blockIdx.x;
    const int gt = b * 256 + t;
    if (gt < 1024) counts[gt] = 0u;
    const int kl = t >> 2, c = t & 3;
    const int k = b * 64 + kl;
    float* Sw = S + kl * 65 + 16 * c;
    if (k < KM1) {
        float tt = dither[k];
        const float4* lo4 = (const float4*)(cb + (size_t)k * 64 + 16 * c);
        const float4* hi4 = (const float4*)(cb + (size_t)(k + 1) * 64 + 16 * c);
        #pragma unroll
        for (int q = 0; q < 4; ++q) {
            float4 lo = lo4[q], hi = hi4[q];
            Sw[4 * q + 0] = lerp_exact(lo.x, hi.x, tt);
            Sw[4 * q + 1] = lerp_exact(lo.y, hi.y, tt);
            Sw[4 * q + 2] = lerp_exact(lo.z, hi.z, tt);
            Sw[4 * q + 3] = lerp_exact(lo.w, hi.w, tt);
        }
    } else {
        #pragma unroll
        for (int q = 0; q < 16; ++q) Sw[q] = 0.f;
    }
    __syncthreads();
    if (t < 64) {  // d2 via numpy 8-accumulator pairwise over fl(d^2)
        const float* Sr = S + t * 65;
        float r[8];
        #pragma unroll
        for (int j = 0; j < 8; ++j) {
            float x = Sr[j]; float bb = __fmul_rn(x, x); OPQ(bb); r[j] = bb;
        }
        #pragma unroll
        for (int i = 8; i < 64; i += 8) {
            #pragma unroll
            for (int j = 0; j < 8; ++j) {
                float x = Sr[i + j]; float bb = __fmul_rn(x, x); OPQ(bb);
                r[j] = __fadd_rn(r[j], bb);
            }
        }
        float s = __fadd_rn(
            __fadd_rn(__fadd_rn(r[0], r[1]), __fadd_rn(r[2], r[3])),
            __fadd_rn(__fadd_rn(r[4], r[5]), __fadd_rn(r[6], r[7])));
        int kk = b * 64 + t;
        d2[kk] = (kk >= KM1) ? FLT_MAX : s;
    }
    // transposed, doubled write: thread t handles dim i = t>>2, k-chunk c.
    {
        const int i = t >> 2;
        float v[16];
        #pragma unroll
        for (int j = 0; j < 16; ++j) {
            float x = S[(16 * c + j) * 65 + i];
            v[j] = __fadd_rn(x, x);            // exact 2x
        }
        float4* dst = (float4*)(dithT + (size_t)i * KPAD + b * 64 + 16 * c);
        dst[0] = make_float4(v[0], v[1], v[2], v[3]);
        dst[1] = make_float4(v[4], v[5], v[6], v[7]);
        dst[2] = make_float4(v[8], v[9], v[10], v[11]);
        dst[3] = make_float4(v[12], v[13], v[14], v[15]);
    }
}

// Kernel B: zsum[row] = numpy pairwise sum of fl(z_i^2) (bit-exact).
__global__ void __launch_bounds__(256)
zsum_kernel(const float* __restrict__ z_g, float* __restrict__ zs) {
    int row = blockIdx.x * 256 + threadIdx.x;
    const float4* zr = (const float4*)(z_g + (size_t)row * 64);
    float r[8];
    {
        float4 q0 = zr[0], q1 = zr[1];
        float x;
        x = q0.x; x = __fmul_rn(x, x); OPQ(x); r[0] = x;
        x = q0.y; x = __fmul_rn(x, x); OPQ(x); r[1] = x;
        x = q0.z; x = __fmul_rn(x, x); OPQ(x); r[2] = x;
        x = q0.w; x = __fmul_rn(x, x); OPQ(x); r[3] = x;
        x = q1.x; x = __fmul_rn(x, x); OPQ(x); r[4] = x;
        x = q1.y; x = __fmul_rn(x, x); OPQ(x); r[5] = x;
        x = q1.z; x = __fmul_rn(x, x); OPQ(x); r[6] = x;
        x = q1.w; x = __fmul_rn(x, x); OPQ(x); r[7] = x;
    }
    #pragma unroll
    for (int g = 1; g < 8; ++g) {
        float4 q0 = zr[2 * g], q1 = zr[2 * g + 1];
        float x;
        x = q0.x; x = __fmul_rn(x, x); OPQ(x); r[0] = __fadd_rn(r[0], x);
        x = q0.y; x = __fmul_rn(x, x); OPQ(x); r[1] = __fadd_rn(r[1], x);
        x = q0.z; x = __fmul_rn(x, x); OPQ(x); r[2] = __fadd_rn(r[2], x);
        x = q0.w; x = __fmul_rn(x, x); OPQ(x); r[3] = __fadd_rn(r[3], x);
        x = q1.x; x = __fmul_rn(x, x); OPQ(x); r[4] = __fadd_rn(r[4], x);
        x = q1.y; x = __fmul_rn(x, x); OPQ(x); r[5] = __fadd_rn(r[5], x);
        x = q1.z; x = __fmul_rn(x, x); OPQ(x); r[6] = __fadd_rn(r[6], x);
        x = q1.w; x = __fmul_rn(x, x); OPQ(x); r[7] = __fadd_rn(r[7], x);
    }
    zs[row] = __fadd_rn(
        __fadd_rn(__fadd_rn(r[0], r[1]), __fadd_rn(r[2], r[3])),
        __fadd_rn(__fadd_rn(r[4], r[5]), __fadd_rn(r[6], r[7])));
}

// Kernel C: argmin, SGEMM-style 4x4 register blocking.
// Block = 64 rows x 1023 k; 4 waves stack k (wave w: k = t*64 + 16w .. +15).
// Lane (rg=lane>>2, kg=lane&3): rows 4rg..+3, k-quad 4kg..+3 of its wave slice.
__global__ void __launch_bounds__(256, 4)
argmin_kernel(const float* __restrict__ z_g,
              const float* __restrict__ dithT,
              const float* __restrict__ d2g,
              const float* __restrict__ zs_g,
              int* __restrict__ idx_out) {
    __shared__ float zT[64 * 68];
    __shared__ float dT[64 * 68];
    __shared__ unsigned long long pack[64];
    const int tid  = threadIdx.x;
    const int wave = tid >> 6;
    const int lane = tid & 63;
    const int rg   = lane >> 2;
    const int kg   = lane & 3;
    const int rowbase = blockIdx.x * 64;
    const int r = tid >> 2;      // staging: row / dim index (0..63)
    const int c = tid & 3;       // staging: 16-float chunk

    // Stage zT transposed: zT[dim][row].
    {
        const float4* src = (const float4*)(z_g + (size_t)(rowbase + r) * 64 + 16 * c);
        float4 a0 = src[0], a1 = src[1], a2 = src[2], a3 = src[3];
        float* zc = zT + (16 * c) * 68 + r;
        zc[0 * 68] = a0.x;  zc[1 * 68] = a0.y;  zc[2 * 68] = a0.z;  zc[3 * 68] = a0.w;
        zc[4 * 68] = a1.x;  zc[5 * 68] = a1.y;  zc[6 * 68] = a1.z;  zc[7 * 68] = a1.w;
        zc[8 * 68] = a2.x;  zc[9 * 68] = a2.y;  zc[10 * 68] = a2.z; zc[11 * 68] = a2.w;
        zc[12 * 68] = a3.x; zc[13 * 68] = a3.y; zc[14 * 68] = a3.z; zc[15 * 68] = a3.w;
    }
    if (tid < 64) pack[tid] = ~0ull;
    const float4 zs = *(const float4*)(zs_g + rowbase + 4 * rg);

    // Prologue: tile 0 global -> regs.
    const float* gsrc = dithT + (size_t)r * KPAD + 16 * c;
    float4 s0, s1, s2, s3;
    { const float4* p = (const float4*)gsrc; s0 = p[0]; s1 = p[1]; s2 = p[2]; s3 = p[3]; }
    __syncthreads();                       // zT + pack ready
    {
        float4* d = (float4*)(dT + r * 68 + 16 * c);
        d[0] = s0; d[1] = s1; d[2] = s2; d[3] = s3;
    }
    __syncthreads();                       // dT tile 0 ready

    float b0 = FLT_MAX, b1 = FLT_MAX, b2 = FLT_MAX, b3 = FLT_MAX;
    int i0 = 0, i1 = 0, i2 = 0, i3 = 0;
    const int dofs = wave * 16 + 4 * kg;

    #pragma unroll 1
    for (int t = 0; t < 16; ++t) {
        const int k0w = t * 64 + wave * 16;
        const float4 e = *(const float4*)(d2g + k0w + 4 * kg);
        if (t < 15) {                      // async-stage split: issue early
            const float4* p = (const float4*)(gsrc + (t + 1) * 64);
            s0 = p[0]; s1 = p[1]; s2 = p[2]; s3 = p[3];
        }
        float a00, a01, a02, a03, a10, a11, a12, a13;
        float a20, a21, a22, a23, a30, a31, a32, a33;
        {
            const float4 zq = *(const float4*)(zT + 4 * rg);
            const float4 dq = *(const float4*)(dT + dofs);
            a00 = __fmul_rn(zq.x, dq.x); a01 = __fmul_rn(zq.x, dq.y);
            a02 = __fmul_rn(zq.x, dq.z); a03 = __fmul_rn(zq.x, dq.w);
            a10 = __fmul_rn(zq.y, dq.x); a11 = __fmul_rn(zq.y, dq.y);
            a12 = __fmul_rn(zq.y, dq.z); a13 = __fmul_rn(zq.y, dq.w);
            a20 = __fmul_rn(zq.z, dq.x); a21 = __fmul_rn(zq.z, dq.y);
            a22 = __fmul_rn(zq.z, dq.z); a23 = __fmul_rn(zq.z, dq.w);
            a30 = __fmul_rn(zq.w, dq.x); a31 = __fmul_rn(zq.w, dq.y);
            a32 = __fmul_rn(zq.w, dq.z); a33 = __fmul_rn(zq.w, dq.w);
        }
        #pragma unroll
        for (int i = 1; i < 64; ++i) {
            const float4 zq = *(const float4*)(zT + i * 68 + 4 * rg);
            const float4 dq = *(const float4*)(dT + i * 68 + dofs);
            a00 = fmaf(zq.x, dq.x, a00); a01 = fmaf(zq.x, dq.y, a01);
            a02 = fmaf(zq.x, dq.z, a02); a03 = fmaf(zq.x, dq.w, a03);
            a10 = fmaf(zq.y, dq.x, a10); a11 = fmaf(zq.y, dq.y, a11);
            a12 = fmaf(zq.y, dq.z, a12); a13 = fmaf(zq.y, dq.w, a13);
            a20 = fmaf(zq.z, dq.x, a20); a21 = fmaf(zq.z, dq.y, a21);
            a22 = fmaf(zq.z, dq.z, a22); a23 = fmaf(zq.z, dq.w, a23);
            a30 = fmaf(zq.w, dq.x, a30); a31 = fmaf(zq.w, dq.y, a31);
            a32 = fmaf(zq.w, dq.z, a32); a33 = fmaf(zq.w, dq.w, a33);
        }
        const int kb = k0w + 4 * kg;
        float D;
        D = __fsub_rn(__fadd_rn(zs.x, e.x), a00); if (D < b0) { b0 = D; i0 = kb + 0; }
        D = __fsub_rn(__fadd_rn(zs.x, e.y), a01); if (D < b0) { b0 = D; i0 = kb + 1; }
        D = __fsub_rn(__fadd_rn(zs.x, e.z), a02); if (D < b0) { b0 = D; i0 = kb + 2; }
        D = __fsub_rn(__fadd_rn(zs.x, e.w), a03); if (D < b0) { b0 = D; i0 = kb + 3; }
        D = __fsub_rn(__fadd_rn(zs.y, e.x), a10); if (D < b1) { b1 = D; i1 = kb + 0; }
        D = __fsub_rn(__fadd_rn(zs.y, e.y), a11); if (D < b1) { b1 = D; i1 = kb + 1; }
        D = __fsub_rn(__fadd_rn(zs.y, e.z), a12); if (D < b1) { b1 = D; i1 = kb + 2; }
        D = __fsub_rn(__fadd_rn(zs.y, e.w), a13); if (D < b1) { b1 = D; i1 = kb + 3; }
        D = __fsub_rn(__fadd_rn(zs.z, e.x), a20); if (D < b2) { b2 = D; i2 = kb + 0; }
        D = __fsub_rn(__fadd_rn(zs.z, e.y), a21); if (D < b2) { b2 = D; i2 = kb + 1; }
        D = __fsub_rn(__fadd_rn(zs.z, e.z), a22); if (D < b2) { b2 = D; i2 = kb + 2; }
        D = __fsub_rn(__fadd_rn(zs.z, e.w), a23); if (D < b2) { b2 = D; i2 = kb + 3; }
        D = __fsub_rn(__fadd_rn(zs.w, e.x), a30); if (D < b3) { b3 = D; i3 = kb + 0; }
        D = __fsub_rn(__fadd_rn(zs.w, e.y), a31); if (D < b3) { b3 = D; i3 = kb + 1; }
        D = __fsub_rn(__fadd_rn(zs.w, e.z), a32); if (D < b3) { b3 = D; i3 = kb + 2; }
        D = __fsub_rn(__fadd_rn(zs.w, e.w), a33); if (D < b3) { b3 = D; i3 = kb + 3; }
        __syncthreads();                   // everyone done reading dT tile t
        if (t < 15) {
            float4* d = (float4*)(dT + r * 68 + 16 * c);
            d[0] = s0; d[1] = s1; d[2] = s2; d[3] = s3;
        }
        __syncthreads();                   // dT tile t+1 ready
    }
    // kg-merge (ties -> smaller k), then packed LDS atomicMin across waves.
    #pragma unroll
    for (int d = 1; d <= 2; d <<= 1) {
        float ov; int ok;
        ov = __shfl_xor(b0, d); ok = __shfl_xor(i0, d);
        if (ov < b0 || (ov == b0 && ok < i0)) { b0 = ov; i0 = ok; }
        ov = __shfl_xor(b1, d); ok = __shfl_xor(i1, d);
        if (ov < b1 || (ov == b1 && ok < i1)) { b1 = ov; i1 = ok; }
        ov = __shfl_xor(b2, d); ok = __shfl_xor(i2, d);
        if (ov < b2 || (ov == b2 && ok < i2)) { b2 = ov; i2 = ok; }
        ov = __shfl_xor(b3, d); ok = __shfl_xor(i3, d);
        if (ov < b3 || (ov == b3 && ok < i3)) { b3 = ov; i3 = ok; }
    }
    if (kg == 0) {
        atomicMin(&pack[4 * rg + 0], ((unsigned long long)__float_as_uint(b0) << 32) | (unsigned)i0);
        atomicMin(&pack[4 * rg + 1], ((unsigned long long)__float_as_uint(b1) << 32) | (unsigned)i1);
        atomicMin(&pack[4 * rg + 2], ((unsigned long long)__float_as_uint(b2) << 32) | (unsigned)i2);
        atomicMin(&pack[4 * rg + 3], ((unsigned long long)__float_as_uint(b3) << 32) | (unsigned)i3);
    }
    __syncthreads();
    if (tid < 64) idx_out[rowbase + tid] = (int)(pack[tid] & 0xffffffffu);
}

// Kernel D: per-row finalize. One wave per row (lane = dim).
__global__ void __launch_bounds__(256)
finalize_kernel(const float* __restrict__ z_g,
                const float* __restrict__ cb,
                const float* __restrict__ dither,
                const float* __restrict__ n1_g,
                const float* __restrict__ n2_g,
                const int* __restrict__ idx_arr,
                float* __restrict__ zq_out,
                float* __restrict__ idxf_out,
                unsigned* __restrict__ counts) {
    int wid = (blockIdx.x * 256 + threadIdx.x) >> 6;
    int lane = threadIdx.x & 63;
    int idx = idx_arr[wid];
    size_t base = (size_t)wid * DIM + lane;
    float z  = z_g[base];
    float n1 = n1_g[base];
    float n2 = n2_g[base];
    float c1 = cb[idx * DIM + lane];
    float c2 = cb[(idx + 1) * DIM + lane];
    float lam = dither[idx];
    float d1 = c1 - z, d2v = c2 - z;
    float r1 = n1 + d1, r2 = n2 + d2v;
    float s_r1 = r1 * r1, s_r2 = r2 * r2, s_d1 = d1 * d1, s_d2 = d2v * d2v;
    #pragma unroll
    for (int m = 32; m; m >>= 1) {
        s_r1 += __shfl_xor(s_r1, m, 64);
        s_r2 += __shfl_xor(s_r2, m, 64);
        s_d1 += __shfl_xor(s_d1, m, 64);
        s_d2 += __shfl_xor(s_d2, m, 64);
    }
    float em1 = sqrtf(s_d1), em2 = sqrtf(s_d2);
    float nr1 = fmaxf(sqrtf(s_r1), 1e-12f);
    float nr2 = fmaxf(sqrtf(s_r2), 1e-12f);
    float zq = z + em1 * (1.f - lam) * (r1 / nr1) + em2 * lam * (r2 / nr2);
    zq_out[base] = zq;
    if (lane == 0) {
        idxf_out[wid] = (float)idx;
        atomicAdd(&counts[idx], 1u);
    }
}

// Kernel E: perplexity from counts.
__global__ void ppl_kernel(const unsigned* __restrict__ counts,
                           float* __restrict__ out) {
    __shared__ float partial[16];
    int t = threadIdx.x;
    float p = (float)counts[t] * (1.f / (float)N_ROWS);
    float v = (p > 0.f) ? p * logf(p) : 0.f;
    #pragma unroll
    for (int m = 32; m; m >>= 1) v += __shfl_xor(v, m, 64);
    if ((t & 63) == 0) partial[t >> 6] = v;
    __syncthreads();
    if (t < 16) {
        float s = partial[t];
        #pragma unroll
        for (int m = 8; m; m >>= 1) s += __shfl_xor(s, m, 16);
        if (t == 0) out[0] = expf(-s);
    }
}

extern "C" void kernel_launch(void* const* d_in, const int* in_sizes, int n_in,
                              void* d_out, int out_size, void* d_ws, size_t ws_size,
                              hipStream_t stream) {
    const float* z      = (const float*)d_in[0];
    const float* cb     = (const float*)d_in[1];
    const float* dither = (const float*)d_in[2];
    const float* n1     = (const float*)d_in[3];
    const float* n2     = (const float*)d_in[4];

    char* ws = (char*)d_ws;
    float*    dithT  = (float*)(ws + DT_OFF);
    float*    d2     = (float*)(ws + D2_OFF);
    float*    zs     = (float*)(ws + ZS_OFF);
    unsigned* counts = (unsigned*)(ws + CNT_OFF);
    int*      idxa   = (int*)(ws + IDX_OFF);

    float* out  = (float*)d_out;
    float* zq   = out;
    float* idxf = out + (size_t)N_ROWS * DIM;
    float* ppl  = idxf + N_ROWS;

    prep_kernel<<<16, 256, 0, stream>>>(cb, dither, dithT, d2, counts);
    zsum_kernel<<<N_ROWS / 256, 256, 0, stream>>>(z, zs);
    argmin_kernel<<<N_ROWS / 64, 256, 0, stream>>>(z, dithT, d2, zs, idxa);
    finalize_kernel<<<N_ROWS / 4, 256, 0, stream>>>(z, cb, dither, n1, n2,
                                                    idxa, zq, idxf, counts);
    ppl_kernel<<<1, 1024, 0, stream>>>(counts, ppl);
}

// Round 5
// 403.401 us; speedup vs baseline: 21.9583x; 21.9583x over previous
//
#include <hip/hip_runtime.h>
#include <math.h>
#include <float.h>

#define N_ROWS 131072
#define DIM 64
#define KM1 1023
#define KPAD 1024

// ---- ws layout (bytes) ----
#define DT_OFF   0         // float[64][1024] transposed, pre-doubled dith
#define D2_OFF   262144    // float[1024]
#define ZS_OFF   266240    // float[131072] zsum
#define CNT_OFF  790528    // u32[1024]
#define IDX_OFF  794624    // i32[131072]

// Opacity guard: stops ffp-contract=fast from changing rounding vs numpy.
#define OPQ(x) asm volatile("" : "+v"(x))

__device__ __forceinline__ float lerp_exact(float lo, float hi, float tt) {
    float hl = __fsub_rn(hi, lo);
    float p  = __fmul_rn(tt, hl);
    OPQ(p);
    float dv = __fadd_rn(lo, p);
    OPQ(dv);
    return dv;
}

typedef __attribute__((address_space(3))) void lds_void;
typedef __attribute__((address_space(1))) const void glob_void;

__device__ __forceinline__ void stage_chunk(const float* gp, float* lp) {
    // 64 lanes x 16B -> 1KB linear LDS chunk (wave-uniform base + lane*16).
    __builtin_amdgcn_global_load_lds((glob_void*)gp, (lds_void*)lp, 16, 0, 0);
}

// Kernel A: dither + transpose (pre-doubled) + d2 (numpy pairwise) + zero counts.
__global__ void __launch_bounds__(256)
prep_kernel(const float* __restrict__ cb, const float* __restrict__ dither,
            float* __restrict__ dithT, float* __restrict__ d2,
            unsigned* __restrict__ counts) {
    __shared__ float S[64 * 65];
    const int t = threadIdx.x, b = blockIdx.x;
    const int gt = b * 256 + t;
    if (gt < 1024) counts[gt] = 0u;
    const int kl = t >> 2, c = t & 3;
    const int k = b * 64 + kl;
    float* Sw = S + kl * 65 + 16 * c;
    if (k < KM1) {
        float tt = dither[k];
        const float4* lo4 = (const float4*)(cb + (size_t)k * 64 + 16 * c);
        const float4* hi4 = (const float4*)(cb + (size_t)(k + 1) * 64 + 16 * c);
        #pragma unroll
        for (int q = 0; q < 4; ++q) {
            float4 lo = lo4[q], hi = hi4[q];
            Sw[4 * q + 0] = lerp_exact(lo.x, hi.x, tt);
            Sw[4 * q + 1] = lerp_exact(lo.y, hi.y, tt);
            Sw[4 * q + 2] = lerp_exact(lo.z, hi.z, tt);
            Sw[4 * q + 3] = lerp_exact(lo.w, hi.w, tt);
        }
    } else {
        #pragma unroll
        for (int q = 0; q < 16; ++q) Sw[q] = 0.f;
    }
    __syncthreads();
    if (t < 64) {
        const float* Sr = S + t * 65;
        float r[8];
        #pragma unroll
        for (int j = 0; j < 8; ++j) {
            float x = Sr[j]; float bb = __fmul_rn(x, x); OPQ(bb); r[j] = bb;
        }
        #pragma unroll
        for (int i = 8; i < 64; i += 8) {
            #pragma unroll
            for (int j = 0; j < 8; ++j) {
                float x = Sr[i + j]; float bb = __fmul_rn(x, x); OPQ(bb);
                r[j] = __fadd_rn(r[j], bb);
            }
        }
        float s = __fadd_rn(
            __fadd_rn(__fadd_rn(r[0], r[1]), __fadd_rn(r[2], r[3])),
            __fadd_rn(__fadd_rn(r[4], r[5]), __fadd_rn(r[6], r[7])));
        int kk = b * 64 + t;
        d2[kk] = (kk >= KM1) ? FLT_MAX : s;
    }
    {
        const int i = t >> 2;
        float v[16];
        #pragma unroll
        for (int j = 0; j < 16; ++j) {
            float x = S[(16 * c + j) * 65 + i];
            v[j] = __fadd_rn(x, x);            // exact 2x
        }
        float4* dst = (float4*)(dithT + (size_t)i * KPAD + b * 64 + 16 * c);
        dst[0] = make_float4(v[0], v[1], v[2], v[3]);
        dst[1] = make_float4(v[4], v[5], v[6], v[7]);
        dst[2] = make_float4(v[8], v[9], v[10], v[11]);
        dst[3] = make_float4(v[12], v[13], v[14], v[15]);
    }
}

// Kernel B: zsum[row] = numpy pairwise sum of fl(z_i^2) (bit-exact).
__global__ void __launch_bounds__(256)
zsum_kernel(const float* __restrict__ z_g, float* __restrict__ zs) {
    int row = blockIdx.x * 256 + threadIdx.x;
    const float4* zr = (const float4*)(z_g + (size_t)row * 64);
    float r[8];
    {
        float4 q0 = zr[0], q1 = zr[1];
        float x;
        x = q0.x; x = __fmul_rn(x, x); OPQ(x); r[0] = x;
        x = q0.y; x = __fmul_rn(x, x); OPQ(x); r[1] = x;
        x = q0.z; x = __fmul_rn(x, x); OPQ(x); r[2] = x;
        x = q0.w; x = __fmul_rn(x, x); OPQ(x); r[3] = x;
        x = q1.x; x = __fmul_rn(x, x); OPQ(x); r[4] = x;
        x = q1.y; x = __fmul_rn(x, x); OPQ(x); r[5] = x;
        x = q1.z; x = __fmul_rn(x, x); OPQ(x); r[6] = x;
        x = q1.w; x = __fmul_rn(x, x); OPQ(x); r[7] = x;
    }
    #pragma unroll
    for (int g = 1; g < 8; ++g) {
        float4 q0 = zr[2 * g], q1 = zr[2 * g + 1];
        float x;
        x = q0.x; x = __fmul_rn(x, x); OPQ(x); r[0] = __fadd_rn(r[0], x);
        x = q0.y; x = __fmul_rn(x, x); OPQ(x); r[1] = __fadd_rn(r[1], x);
        x = q0.z; x = __fmul_rn(x, x); OPQ(x); r[2] = __fadd_rn(r[2], x);
        x = q0.w; x = __fmul_rn(x, x); OPQ(x); r[3] = __fadd_rn(r[3], x);
        x = q1.x; x = __fmul_rn(x, x); OPQ(x); r[4] = __fadd_rn(r[4], x);
        x = q1.y; x = __fmul_rn(x, x); OPQ(x); r[5] = __fadd_rn(r[5], x);
        x = q1.z; x = __fmul_rn(x, x); OPQ(x); r[6] = __fadd_rn(r[6], x);
        x = q1.w; x = __fmul_rn(x, x); OPQ(x); r[7] = __fadd_rn(r[7], x);
    }
    zs[row] = __fadd_rn(
        __fadd_rn(__fadd_rn(r[0], r[1]), __fadd_rn(r[2], r[3])),
        __fadd_rn(__fadd_rn(r[4], r[5]), __fadd_rn(r[6], r[7])));
}

// Kernel C: argmin. Block = 128 rows x 1023 k. 4 waves = 2 row-halves x
// 2 k-halves; lane=(rg,kg) 8x8; micro-tile 8 rows x 4 k (32 acc).
// dith tiles (64 k) double-buffered via global_load_lds; one barrier/tile.
__global__ void __launch_bounds__(256, 2)
argmin_kernel(const float* __restrict__ z_g,
              const float* __restrict__ dithT,
              const float* __restrict__ d2g,
              const float* __restrict__ zs_g,
              int* __restrict__ idx_out) {
    __shared__ float zT[64][128];       // [dim][row]
    __shared__ float dT[2][4096];       // [64 dims][64 k], linear, pre-doubled
    __shared__ unsigned long long pack[128];
    const int tid  = threadIdx.x;
    const int w    = tid >> 6;
    const int lane = tid & 63;
    const int rg   = lane >> 3;          // 0..7
    const int kg   = lane & 7;           // 0..7
    const int R0   = (w & 1) << 6;       // row-half base
    const int koff = ((w >> 1) << 5) + (kg << 2);   // k-in-tile offset
    const int rowbase = blockIdx.x << 7;

    // Stage zT transposed (one-time).
    {
        const int r = tid >> 1, h = tid & 1;
        const float4* src = (const float4*)(z_g + ((size_t)(rowbase + r) << 6) + (h << 5));
        #pragma unroll
        for (int q = 0; q < 8; ++q) {
            float4 v = src[q];
            zT[(h << 5) + 4 * q + 0][r] = v.x;
            zT[(h << 5) + 4 * q + 1][r] = v.y;
            zT[(h << 5) + 4 * q + 2][r] = v.z;
            zT[(h << 5) + 4 * q + 3][r] = v.w;
        }
    }
    if (tid < 128) pack[tid] = ~0ull;

    float zs8[8];
    {
        float4 a = *(const float4*)(zs_g + rowbase + R0 + (rg << 3));
        float4 c = *(const float4*)(zs_g + rowbase + R0 + (rg << 3) + 4);
        zs8[0] = a.x; zs8[1] = a.y; zs8[2] = a.z; zs8[3] = a.w;
        zs8[4] = c.x; zs8[5] = c.y; zs8[6] = c.z; zs8[7] = c.w;
    }

    // Prologue: tile 0 -> dT[0]. Wave w stages chunks 4w..4w+3 (1KB each).
    #pragma unroll
    for (int j = 0; j < 4; ++j) {
        const int q = 4 * w + j;
        const float* gp = dithT + ((size_t)(4 * q + (lane >> 4)) << 10)
                          + ((lane & 15) << 2);
        stage_chunk(gp, &dT[0][q << 8]);
    }
    __syncthreads();   // zT + pack + tile0 ready (barrier drains vmcnt)

    float b[8]; int bi[8];
    #pragma unroll
    for (int r = 0; r < 8; ++r) { b[r] = FLT_MAX; bi[r] = 0; }

    int cur = 0;
    #pragma unroll 1
    for (int t = 0; t < 16; ++t) {
        const float4 e = *(const float4*)(d2g + (t << 6) + koff);  // before stage
        if (t < 15) {       // async stage of next tile into the other buffer
            #pragma unroll
            for (int j = 0; j < 4; ++j) {
                const int q = 4 * w + j;
                const float* gp = dithT + ((size_t)(4 * q + (lane >> 4)) << 10)
                                  + ((t + 1) << 6) + ((lane & 15) << 2);
                stage_chunk(gp, &dT[cur ^ 1][q << 8]);
            }
        }
        float acc[8][4];
        #pragma unroll
        for (int r = 0; r < 8; ++r) {
            #pragma unroll
            for (int k = 0; k < 4; ++k) acc[r][k] = 0.f;
        }
        const float* dTc = dT[cur];
        #pragma unroll 8
        for (int i = 0; i < 64; ++i) {
            const float4 z0 = *(const float4*)&zT[i][R0 + (rg << 3)];
            const float4 z1 = *(const float4*)&zT[i][R0 + (rg << 3) + 4];
            const float4 dq = *(const float4*)&dTc[(i << 6) + koff];
            const float zz[8] = {z0.x, z0.y, z0.z, z0.w, z1.x, z1.y, z1.z, z1.w};
            const float dd[4] = {dq.x, dq.y, dq.z, dq.w};
            #pragma unroll
            for (int r = 0; r < 8; ++r) {
                #pragma unroll
                for (int k = 0; k < 4; ++k)
                    acc[r][k] = fmaf(zz[r], dd[k], acc[r][k]);
            }
        }
        const int kb = (t << 6) + koff;
        const float ee[4] = {e.x, e.y, e.z, e.w};
        #pragma unroll
        for (int r = 0; r < 8; ++r) {
            #pragma unroll
            for (int k = 0; k < 4; ++k) {
                float D = __fsub_rn(__fadd_rn(zs8[r], ee[k]), acc[r][k]);
                if (D < b[r]) { b[r] = D; bi[r] = kb + k; }
            }
        }
        __syncthreads();   // all reads of dT[cur] done; staged tile landed
        cur ^= 1;
    }

    // kg-octet merge (ties -> smaller k), then packed LDS atomicMin.
    #pragma unroll
    for (int d = 1; d <= 4; d <<= 1) {
        #pragma unroll
        for (int r = 0; r < 8; ++r) {
            float ov = __shfl_xor(b[r], d);
            int   ok = __shfl_xor(bi[r], d);
            if (ov < b[r] || (ov == b[r] && ok < bi[r])) { b[r] = ov; bi[r] = ok; }
        }
    }
    if (kg == 0) {
        #pragma unroll
        for (int r = 0; r < 8; ++r) {
            unsigned long long pk =
                ((unsigned long long)__float_as_uint(b[r]) << 32) | (unsigned)bi[r];
            atomicMin(&pack[R0 + (rg << 3) + r], pk);
        }
    }
    __syncthreads();
    if (tid < 128) idx_out[rowbase + tid] = (int)(pack[tid] & 0xffffffffu);
}

// Kernel D: per-row finalize. One wave per row (lane = dim).
__global__ void __launch_bounds__(256)
finalize_kernel(const float* __restrict__ z_g,
                const float* __restrict__ cb,
                const float* __restrict__ dither,
                const float* __restrict__ n1_g,
                const float* __restrict__ n2_g,
                const int* __restrict__ idx_arr,
                float* __restrict__ zq_out,
                float* __restrict__ idxf_out,
                unsigned* __restrict__ counts) {
    int wid = (blockIdx.x * 256 + threadIdx.x) >> 6;
    int lane = threadIdx.x & 63;
    int idx = idx_arr[wid];
    size_t base = (size_t)wid * DIM + lane;
    float z  = z_g[base];
    float n1 = n1_g[base];
    float n2 = n2_g[base];
    float c1 = cb[idx * DIM + lane];
    float c2 = cb[(idx + 1) * DIM + lane];
    float lam = dither[idx];
    float d1 = c1 - z, d2v = c2 - z;
    float r1 = n1 + d1, r2 = n2 + d2v;
    float s_r1 = r1 * r1, s_r2 = r2 * r2, s_d1 = d1 * d1, s_d2 = d2v * d2v;
    #pragma unroll
    for (int m = 32; m; m >>= 1) {
        s_r1 += __shfl_xor(s_r1, m, 64);
        s_r2 += __shfl_xor(s_r2, m, 64);
        s_d1 += __shfl_xor(s_d1, m, 64);
        s_d2 += __shfl_xor(s_d2, m, 64);
    }
    float em1 = sqrtf(s_d1), em2 = sqrtf(s_d2);
    float nr1 = fmaxf(sqrtf(s_r1), 1e-12f);
    float nr2 = fmaxf(sqrtf(s_r2), 1e-12f);
    float zq = z + em1 * (1.f - lam) * (r1 / nr1) + em2 * lam * (r2 / nr2);
    zq_out[base] = zq;
    if (lane == 0) {
        idxf_out[wid] = (float)idx;
        atomicAdd(&counts[idx], 1u);
    }
}

// Kernel E: perplexity from counts.
__global__ void ppl_kernel(const unsigned* __restrict__ counts,
                           float* __restrict__ out) {
    __shared__ float partial[16];
    int t = threadIdx.x;
    float p = (float)counts[t] * (1.f / (float)N_ROWS);
    float v = (p > 0.f) ? p * logf(p) : 0.f;
    #pragma unroll
    for (int m = 32; m; m >>= 1) v += __shfl_xor(v, m, 64);
    if ((t & 63) == 0) partial[t >> 6] = v;
    __syncthreads();
    if (t < 16) {
        float s = partial[t];
        #pragma unroll
        for (int m = 8; m; m >>= 1) s += __shfl_xor(s, m, 16);
        if (t == 0) out[0] = expf(-s);
    }
}

extern "C" void kernel_launch(void* const* d_in, const int* in_sizes, int n_in,
                              void* d_out, int out_size, void* d_ws, size_t ws_size,
                              hipStream_t stream) {
    const float* z      = (const float*)d_in[0];
    const float* cb     = (const float*)d_in[1];
    const float* dither = (const float*)d_in[2];
    const float* n1     = (const float*)d_in[3];
    const float* n2     = (const float*)d_in[4];

    char* ws = (char*)d_ws;
    float*    dithT  = (float*)(ws + DT_OFF);
    float*    d2     = (float*)(ws + D2_OFF);
    float*    zs     = (float*)(ws + ZS_OFF);
    unsigned* counts = (unsigned*)(ws + CNT_OFF);
    int*      idxa   = (int*)(ws + IDX_OFF);

    float* out  = (float*)d_out;
    float* zq   = out;
    float* idxf = out + (size_t)N_ROWS * DIM;
    float* ppl  = idxf + N_ROWS;

    prep_kernel<<<16, 256, 0, stream>>>(cb, dither, dithT, d2, counts);
    zsum_kernel<<<N_ROWS / 256, 256, 0, stream>>>(z, zs);
    argmin_kernel<<<N_ROWS / 128, 256, 0, stream>>>(z, dithT, d2, zs, idxa);
    finalize_kernel<<<N_ROWS / 4, 256, 0, stream>>>(z, cb, dither, n1, n2,
                                                    idxa, zq, idxf, counts);
    ppl_kernel<<<1, 1024, 0, stream>>>(counts, ppl);
}

// Round 6
// 372.062 us; speedup vs baseline: 23.8078x; 1.0842x over previous
//
#include <hip/hip_runtime.h>
#include <math.h>
#include <float.h>

#define N_ROWS 131072
#define DIM 64
#define KM1 1023
#define KPAD 1024

// ---- ws layout (bytes) ----
#define DT_OFF   0         // float[64][1024] transposed, pre-doubled dith
#define D2_OFF   262144    // float[1024]
#define CNT_OFF  266240    // u32[1024]
#define IDX_OFF  270336    // i32[131072]

// Opacity guard: stops ffp-contract=fast from changing rounding vs numpy.
#define OPQ(x) asm volatile("" : "+v"(x))

__device__ __forceinline__ float lerp_exact(float lo, float hi, float tt) {
    float hl = __fsub_rn(hi, lo);
    float p  = __fmul_rn(tt, hl);
    OPQ(p);
    float dv = __fadd_rn(lo, p);
    OPQ(dv);
    return dv;
}

typedef __attribute__((address_space(3))) void lds_void;
typedef __attribute__((address_space(1))) const void glob_void;

// Kernel A: dither + transpose (pre-doubled) + d2 (numpy pairwise) + zero counts.
__global__ void __launch_bounds__(256)
prep_kernel(const float* __restrict__ cb, const float* __restrict__ dither,
            float* __restrict__ dithT, float* __restrict__ d2,
            unsigned* __restrict__ counts) {
    __shared__ float S[64 * 65];
    const int t = threadIdx.x, b = blockIdx.x;
    const int gt = b * 256 + t;
    if (gt < 1024) counts[gt] = 0u;
    const int kl = t >> 2, c = t & 3;
    const int k = b * 64 + kl;
    float* Sw = S + kl * 65 + 16 * c;
    if (k < KM1) {
        float tt = dither[k];
        const float4* lo4 = (const float4*)(cb + (size_t)k * 64 + 16 * c);
        const float4* hi4 = (const float4*)(cb + (size_t)(k + 1) * 64 + 16 * c);
        #pragma unroll
        for (int q = 0; q < 4; ++q) {
            float4 lo = lo4[q], hi = hi4[q];
            Sw[4 * q + 0] = lerp_exact(lo.x, hi.x, tt);
            Sw[4 * q + 1] = lerp_exact(lo.y, hi.y, tt);
            Sw[4 * q + 2] = lerp_exact(lo.z, hi.z, tt);
            Sw[4 * q + 3] = lerp_exact(lo.w, hi.w, tt);
        }
    } else {
        #pragma unroll
        for (int q = 0; q < 16; ++q) Sw[q] = 0.f;
    }
    __syncthreads();
    if (t < 64) {
        const float* Sr = S + t * 65;
        float r[8];
        #pragma unroll
        for (int j = 0; j < 8; ++j) {
            float x = Sr[j]; float bb = __fmul_rn(x, x); OPQ(bb); r[j] = bb;
        }
        #pragma unroll
        for (int i = 8; i < 64; i += 8) {
            #pragma unroll
            for (int j = 0; j < 8; ++j) {
                float x = Sr[i + j]; float bb = __fmul_rn(x, x); OPQ(bb);
                r[j] = __fadd_rn(r[j], bb);
            }
        }
        float s = __fadd_rn(
            __fadd_rn(__fadd_rn(r[0], r[1]), __fadd_rn(r[2], r[3])),
            __fadd_rn(__fadd_rn(r[4], r[5]), __fadd_rn(r[6], r[7])));
        int kk = b * 64 + t;
        d2[kk] = (kk >= KM1) ? FLT_MAX : s;
    }
    {
        const int i = t >> 2;
        float v[16];
        #pragma unroll
        for (int j = 0; j < 16; ++j) {
            float x = S[(16 * c + j) * 65 + i];
            v[j] = __fadd_rn(x, x);            // exact 2x
        }
        float4* dst = (float4*)(dithT + (size_t)i * KPAD + b * 64 + 16 * c);
        dst[0] = make_float4(v[0], v[1], v[2], v[3]);
        dst[1] = make_float4(v[4], v[5], v[6], v[7]);
        dst[2] = make_float4(v[8], v[9], v[10], v[11]);
        dst[3] = make_float4(v[12], v[13], v[14], v[15]);
    }
}

// Kernel B: argmin. Block = 128 rows x 1023 k, 8 tiles of 128 k.
// 4 waves = 2 row-halves x 2 k-halves; lane = (rg,kg) 8x8; micro-tile
// 8 rows x 8 k (64 acc). dT single-buffered [64 dims][128 k], staged via
// global_load_lds; zsum fused (computed from zT). Bit-exact numpy scoring.
__global__ void __launch_bounds__(256, 2)
argmin_kernel(const float* __restrict__ z_g,
              const float* __restrict__ dithT,
              const float* __restrict__ d2g,
              int* __restrict__ idx_out) {
    __shared__ float zT[64][128];        // [dim][row]   32 KB
    __shared__ float dTl[64 * 128];      // [dim][k]     32 KB, pre-doubled
    __shared__ float zsArr[128];
    __shared__ unsigned long long pack[128];
    const int tid  = threadIdx.x;
    const int w    = tid >> 6;
    const int lane = tid & 63;
    const int rg   = lane >> 3;               // 0..7
    const int kg   = lane & 7;                // 0..7
    const int R0   = (w & 1) << 6;            // row-half base
    const int KH   = (w >> 1) << 6;           // k-half base within 128-k tile
    const int rowbase = blockIdx.x << 7;

    // Stage zT transposed (one-time): thread = (row r, half h).
    {
        const int r = tid >> 1, h = tid & 1;
        const float4* src =
            (const float4*)(z_g + ((size_t)(rowbase + r) << 6) + (h << 5));
        #pragma unroll
        for (int q = 0; q < 8; ++q) {
            float4 v = src[q];
            zT[(h << 5) + 4 * q + 0][r] = v.x;
            zT[(h << 5) + 4 * q + 1][r] = v.y;
            zT[(h << 5) + 4 * q + 2][r] = v.z;
            zT[(h << 5) + 4 * q + 3][r] = v.w;
        }
    }
    if (tid < 128) pack[tid] = ~0ull;

    // Issue tile 0 stage: wave w loads chunks 8w..8w+7 (1 KB = 2 dim-rows).
    #pragma unroll
    for (int j = 0; j < 8; ++j) {
        const int q = 8 * w + j;
        const int dim = 2 * q + (lane >> 5);
        const float* gp = dithT + ((size_t)dim << 10) + ((lane & 31) << 2);
        __builtin_amdgcn_global_load_lds((glob_void*)gp,
                                         (lds_void*)(dTl + (q << 8)), 16, 0, 0);
    }
    __syncthreads();   // zT + pack + tile0 ready (barrier drains vmcnt)

    // Fused zsum: thread r computes numpy-pairwise sum of fl(z^2) from zT.
    if (tid < 128) {
        float acc8[8];
        #pragma unroll
        for (int m = 0; m < 8; ++m) {
            #pragma unroll
            for (int j = 0; j < 8; ++j) {
                float x = zT[8 * m + j][tid];
                float sq = __fmul_rn(x, x); OPQ(sq);
                acc8[j] = (m == 0) ? sq : __fadd_rn(acc8[j], sq);
            }
        }
        zsArr[tid] = __fadd_rn(
            __fadd_rn(__fadd_rn(acc8[0], acc8[1]), __fadd_rn(acc8[2], acc8[3])),
            __fadd_rn(__fadd_rn(acc8[4], acc8[5]), __fadd_rn(acc8[6], acc8[7])));
    }
    __syncthreads();

    float zs8[8];
    #pragma unroll
    for (int r = 0; r < 8; ++r) zs8[r] = zsArr[R0 + (rg << 3) + r];

    float b[8]; int bi[8];
    #pragma unroll
    for (int r = 0; r < 8; ++r) { b[r] = FLT_MAX; bi[r] = 0; }

    const float* zrow = &zT[0][R0 + (rg << 3)];
    const float* drow = &dTl[KH + (kg << 3)];

    #pragma unroll 1
    for (int t = 0; t < 8; ++t) {
        const int kb = (t << 7) + KH + (kg << 3);
        const float4 ea = *(const float4*)(d2g + kb);
        const float4 eb = *(const float4*)(d2g + kb + 4);

        float acc[8][8];
        #pragma unroll
        for (int r = 0; r < 8; ++r) {
            #pragma unroll
            for (int k = 0; k < 8; ++k) acc[r][k] = 0.f;
        }
        #pragma unroll 4
        for (int i = 0; i < 64; ++i) {
            const float4 z0 = *(const float4*)(zrow + i * 128);
            const float4 z1 = *(const float4*)(zrow + i * 128 + 4);
            const float4 d0 = *(const float4*)(drow + i * 128);
            const float4 d1 = *(const float4*)(drow + i * 128 + 4);
            const float zz[8] = {z0.x, z0.y, z0.z, z0.w, z1.x, z1.y, z1.z, z1.w};
            const float dd[8] = {d0.x, d0.y, d0.z, d0.w, d1.x, d1.y, d1.z, d1.w};
            #pragma unroll
            for (int r = 0; r < 8; ++r) {
                #pragma unroll
                for (int k = 0; k < 8; ++k)
                    acc[r][k] = fmaf(zz[r], dd[k], acc[r][k]);
            }
        }
        const float ee[8] = {ea.x, ea.y, ea.z, ea.w, eb.x, eb.y, eb.z, eb.w};
        #pragma unroll
        for (int r = 0; r < 8; ++r) {
            #pragma unroll
            for (int k = 0; k < 8; ++k) {
                float D = __fsub_rn(__fadd_rn(zs8[r], ee[k]), acc[r][k]);
                if (D < b[r]) { b[r] = D; bi[r] = kb + k; }
            }
        }
        __syncthreads();           // all waves done reading dTl tile t
        if (t < 7) {               // stage tile t+1 (single buffer)
            #pragma unroll
            for (int j = 0; j < 8; ++j) {
                const int q = 8 * w + j;
                const int dim = 2 * q + (lane >> 5);
                const float* gp = dithT + ((size_t)dim << 10)
                                  + ((t + 1) << 7) + ((lane & 31) << 2);
                __builtin_amdgcn_global_load_lds((glob_void*)gp,
                                                 (lds_void*)(dTl + (q << 8)),
                                                 16, 0, 0);
            }
        }
        __syncthreads();           // staged tile landed (vmcnt drained)
    }

    // kg-octet merge (ties -> smaller k), then packed LDS atomicMin.
    #pragma unroll
    for (int d = 1; d <= 4; d <<= 1) {
        #pragma unroll
        for (int r = 0; r < 8; ++r) {
            float ov = __shfl_xor(b[r], d);
            int   ok = __shfl_xor(bi[r], d);
            if (ov < b[r] || (ov == b[r] && ok < bi[r])) { b[r] = ov; bi[r] = ok; }
        }
    }
    if (kg == 0) {
        #pragma unroll
        for (int r = 0; r < 8; ++r) {
            unsigned long long pk =
                ((unsigned long long)__float_as_uint(b[r]) << 32) | (unsigned)bi[r];
            atomicMin(&pack[R0 + (rg << 3) + r], pk);
        }
    }
    __syncthreads();
    if (tid < 128) idx_out[rowbase + tid] = (int)(pack[tid] & 0xffffffffu);
}

// Kernel C: per-row finalize. One wave per row (lane = dim).
__global__ void __launch_bounds__(256)
finalize_kernel(const float* __restrict__ z_g,
                const float* __restrict__ cb,
                const float* __restrict__ dither,
                const float* __restrict__ n1_g,
                const float* __restrict__ n2_g,
                const int* __restrict__ idx_arr,
                float* __restrict__ zq_out,
                float* __restrict__ idxf_out,
                unsigned* __restrict__ counts) {
    int wid = (blockIdx.x * 256 + threadIdx.x) >> 6;
    int lane = threadIdx.x & 63;
    int idx = idx_arr[wid];
    size_t base = (size_t)wid * DIM + lane;
    float z  = z_g[base];
    float n1 = n1_g[base];
    float n2 = n2_g[base];
    float c1 = cb[idx * DIM + lane];
    float c2 = cb[(idx + 1) * DIM + lane];
    float lam = dither[idx];
    float d1 = c1 - z, d2v = c2 - z;
    float r1 = n1 + d1, r2 = n2 + d2v;
    float s_r1 = r1 * r1, s_r2 = r2 * r2, s_d1 = d1 * d1, s_d2 = d2v * d2v;
    #pragma unroll
    for (int m = 32; m; m >>= 1) {
        s_r1 += __shfl_xor(s_r1, m, 64);
        s_r2 += __shfl_xor(s_r2, m, 64);
        s_d1 += __shfl_xor(s_d1, m, 64);
        s_d2 += __shfl_xor(s_d2, m, 64);
    }
    float em1 = sqrtf(s_d1), em2 = sqrtf(s_d2);
    float nr1 = fmaxf(sqrtf(s_r1), 1e-12f);
    float nr2 = fmaxf(sqrtf(s_r2), 1e-12f);
    float zq = z + em1 * (1.f - lam) * (r1 / nr1) + em2 * lam * (r2 / nr2);
    zq_out[base] = zq;
    if (lane == 0) {
        idxf_out[wid] = (float)idx;
        atomicAdd(&counts[idx], 1u);
    }
}

// Kernel D: perplexity from counts.
__global__ void ppl_kernel(const unsigned* __restrict__ counts,
                           float* __restrict__ out) {
    __shared__ float partial[16];
    int t = threadIdx.x;
    float p = (float)counts[t] * (1.f / (float)N_ROWS);
    float v = (p > 0.f) ? p * logf(p) : 0.f;
    #pragma unroll
    for (int m = 32; m; m >>= 1) v += __shfl_xor(v, m, 64);
    if ((t & 63) == 0) partial[t >> 6] = v;
    __syncthreads();
    if (t < 16) {
        float s = partial[t];
        #pragma unroll
        for (int m = 8; m; m >>= 1) s += __shfl_xor(s, m, 16);
        if (t == 0) out[0] = expf(-s);
    }
}

extern "C" void kernel_launch(void* const* d_in, const int* in_sizes, int n_in,
                              void* d_out, int out_size, void* d_ws, size_t ws_size,
                              hipStream_t stream) {
    const float* z      = (const float*)d_in[0];
    const float* cb     = (const float*)d_in[1];
    const float* dither = (const float*)d_in[2];
    const float* n1     = (const float*)d_in[3];
    const float* n2     = (const float*)d_in[4];

    char* ws = (char*)d_ws;
    float*    dithT  = (float*)(ws + DT_OFF);
    float*    d2     = (float*)(ws + D2_OFF);
    unsigned* counts = (unsigned*)(ws + CNT_OFF);
    int*      idxa   = (int*)(ws + IDX_OFF);

    float* out  = (float*)d_out;
    float* zq   = out;
    float* idxf = out + (size_t)N_ROWS * DIM;
    float* ppl  = idxf + N_ROWS;

    prep_kernel<<<16, 256, 0, stream>>>(cb, dither, dithT, d2, counts);
    argmin_kernel<<<N_ROWS / 128, 256, 0, stream>>>(z, dithT, d2, idxa);
    finalize_kernel<<<N_ROWS / 4, 256, 0, stream>>>(z, cb, dither, n1, n2,
                                                    idxa, zq, idxf, counts);
    ppl_kernel<<<1, 1024, 0, stream>>>(counts, ppl);
}